// Round 1
// baseline (687.130 us; speedup 1.0000x reference)
//
#include <hip/hip_runtime.h>
#include <hip/hip_bf16.h>

typedef __attribute__((ext_vector_type(4))) float  f32x4;
typedef __attribute__((ext_vector_type(8))) short  bf16x8;
typedef __attribute__((ext_vector_type(4))) short  short4_t;
typedef unsigned short u16;

#define SCALE_Q 0.17677669529663687f   // 32^-0.5

__device__ __forceinline__ u16 f2bf(float f) {
    union { float f; unsigned u; } v; v.f = f;
    unsigned u = v.u;
    return (u16)((u + 0x7FFFu + ((u >> 16) & 1u)) >> 16);  // RNE
}

__device__ __forceinline__ short4_t f4tobf(float4 f) {
    short4_t h;
    h.x = (short)f2bf(f.x); h.y = (short)f2bf(f.y);
    h.z = (short)f2bf(f.z); h.w = (short)f2bf(f.w);
    return h;
}

// ---------------------------------------------------------------------------
// cwb[w][h][i][j] = bias_table[REL_IDX[i][j]][h] + mask[w][i][j]   (fp32)
// i = query token, j = key token; layout row-major in (i,j).
// ---------------------------------------------------------------------------
__global__ __launch_bounds__(256) void cwb_kernel(
        const float* __restrict__ bias_table,   // [225][16]
        const float* __restrict__ mask,         // [64][64][64]
        float* __restrict__ cwb)                // [64][16][64][64]
{
    const int wh = blockIdx.x;          // w*16 + h
    const int w = wh >> 4, h = wh & 15;
    for (int e = threadIdx.x; e < 4096; e += 256) {
        const int i = e >> 6, j = e & 63;
        const int rel = ((i >> 3) - (j >> 3) + 7) * 15 + (i & 7) - (j & 7) + 7;
        cwb[(size_t)wh * 4096 + e] = bias_table[rel * 16 + h] + mask[(size_t)w * 4096 + e];
    }
}

// ---------------------------------------------------------------------------
// GEMM: C[M=65536, N=512] = A[M,512] @ W[N=512,512]^T + bias (, * scale)
// AMODE: 0 = A fp32 (convert to bf16 on stage), 1 = A bf16 (u16)
// OMODE: 0 = bf16 out at [b][h][t][d]   (q,k heads layout)
//        1 = bf16 out at [b][h][d][t]   (v transposed heads layout)
//        2 = fp32 out row-major [m][n]  (final projection)
// Tile 128x128, BK=64, 4 waves (2x2), 16x16x32 bf16 MFMA.
// LDS XOR swizzle: element (row,col) at ushort idx (row*64+col)^((row&7)<<3).
// ---------------------------------------------------------------------------
template<int AMODE, int OMODE>
__global__ __launch_bounds__(256) void gemm_k(
        const void* __restrict__ Aptr, const float* __restrict__ W,
        const float* __restrict__ bias, float scale, void* __restrict__ outp)
{
    __shared__ __align__(16) u16 As[8192];
    __shared__ __align__(16) u16 Bs[8192];

    const int t  = threadIdx.x;
    const int m0 = blockIdx.y << 7;
    const int n0 = blockIdx.x << 7;
    const int wv = t >> 6, lane = t & 63, g = lane >> 4, ln = lane & 15;
    const int wr = wv >> 1, wc = wv & 1;

    f32x4 acc[4][4];
#pragma unroll
    for (int i = 0; i < 4; i++)
#pragma unroll
        for (int j = 0; j < 4; j++) acc[i][j] = {0.f, 0.f, 0.f, 0.f};

    for (int k0 = 0; k0 < 512; k0 += 64) {
        // ---- stage A tile (128 x 64) ----
        if (AMODE == 0) {
            const float* A = (const float*)Aptr;
            const int row = t >> 1, cb = (t & 1) << 5;
            const float4* src = (const float4*)(A + (size_t)(m0 + row) * 512 + k0 + cb);
#pragma unroll
            for (int c = 0; c < 8; c++) {
                const int idx = (row * 64 + cb + c * 4) ^ ((row & 7) << 3);
                *(short4_t*)&As[idx] = f4tobf(src[c]);
            }
        } else {
            const u16* A = (const u16*)Aptr;
            const int row = t >> 1, cb = (t & 1) << 5;
            const int4* src = (const int4*)(A + (size_t)(m0 + row) * 512 + k0 + cb);
#pragma unroll
            for (int c = 0; c < 4; c++) {
                const int idx = (row * 64 + cb + c * 8) ^ ((row & 7) << 3);
                *(int4*)&As[idx] = src[c];
            }
        }
        // ---- stage B tile (W rows n0..n0+127, fp32 -> bf16) ----
        {
            const int row = t >> 1, cb = (t & 1) << 5;
            const float4* src = (const float4*)(W + (size_t)(n0 + row) * 512 + k0 + cb);
#pragma unroll
            for (int c = 0; c < 8; c++) {
                const int idx = (row * 64 + cb + c * 4) ^ ((row & 7) << 3);
                *(short4_t*)&Bs[idx] = f4tobf(src[c]);
            }
        }
        __syncthreads();
#pragma unroll
        for (int ks = 0; ks < 2; ks++) {
            bf16x8 af[4], bfr[4];
#pragma unroll
            for (int mt = 0; mt < 4; mt++) {
                const int row = (wr << 6) + (mt << 4) + ln, col = (ks << 5) + (g << 3);
                af[mt] = *(const bf16x8*)&As[(row * 64 + col) ^ ((row & 7) << 3)];
            }
#pragma unroll
            for (int nt = 0; nt < 4; nt++) {
                const int row = (wc << 6) + (nt << 4) + ln, col = (ks << 5) + (g << 3);
                bfr[nt] = *(const bf16x8*)&Bs[(row * 64 + col) ^ ((row & 7) << 3)];
            }
#pragma unroll
            for (int mt = 0; mt < 4; mt++)
#pragma unroll
                for (int nt = 0; nt < 4; nt++)
                    acc[mt][nt] = __builtin_amdgcn_mfma_f32_16x16x32_bf16(
                        af[mt], bfr[nt], acc[mt][nt], 0, 0, 0);
        }
        __syncthreads();
    }

    // ---- epilogue: bias, scale, store ----
#pragma unroll
    for (int mt = 0; mt < 4; mt++) {
#pragma unroll
        for (int nt = 0; nt < 4; nt++) {
            const int n = n0 + (wc << 6) + (nt << 4) + ln;
            const float bv = bias[n];
            const int mbase = m0 + (wr << 6) + (mt << 4) + (g << 2);
            if (OMODE == 0) {
#pragma unroll
                for (int r = 0; r < 4; r++) {
                    const int m = mbase + r;
                    const int b = m >> 6, tt = m & 63, hh = n >> 5, d = n & 31;
                    ((u16*)outp)[((size_t)(b * 16 + hh) * 64 + tt) * 32 + d] =
                        f2bf((acc[mt][nt][r] + bv) * scale);
                }
            } else if (OMODE == 1) {
                short4_t hq;
#pragma unroll
                for (int r = 0; r < 4; r++) hq[r] = (short)f2bf((acc[mt][nt][r] + bv) * scale);
                const int b = mbase >> 6, tt = mbase & 63, hh = n >> 5, d = n & 31;
                *(short4_t*)&((u16*)outp)[((size_t)(b * 16 + hh) * 32 + d) * 64 + tt] = hq;
            } else {
#pragma unroll
                for (int r = 0; r < 4; r++) {
                    const int m = mbase + r;
                    ((float*)outp)[(size_t)m * 512 + n] = (acc[mt][nt][r] + bv) * scale;
                }
            }
        }
    }
}

// ---------------------------------------------------------------------------
// Attention: one wave per (b,h). S^T = K·Q^T via mfma(K,Q) so the 4 C-regs are
// key-index(j)-consecutive; softmax over j needs only local reduce + shfl_xor
// 16/32. P written to LDS row-major [i][j] (XOR-swizzled), PV as O^T = V^T · P.
// qh,kh: [b][h][t][d] bf16 ; vt: [b][h][d][t] bf16 ; x out: [b][t][h*32+d] bf16
// ---------------------------------------------------------------------------
__global__ __launch_bounds__(64) void attn_kernel(
        const u16* __restrict__ qh, const u16* __restrict__ kh,
        const u16* __restrict__ vt, const float* __restrict__ cwb,
        u16* __restrict__ xout)
{
    __shared__ __align__(16) u16 P[4096];

    const int bid = blockIdx.x;                 // b*16 + h
    const int b = bid >> 4, h = bid & 15, w = b & 63;
    const int lane = threadIdx.x, g = lane >> 4, ln = lane & 15;
    const size_t base = (size_t)bid * 2048;

    bf16x8 kf[4], qf[4];
#pragma unroll
    for (int mt = 0; mt < 4; mt++)
        kf[mt] = *(const bf16x8*)&kh[base + (mt * 16 + ln) * 32 + g * 8];
#pragma unroll
    for (int nt = 0; nt < 4; nt++)
        qf[nt] = *(const bf16x8*)&qh[base + (nt * 16 + ln) * 32 + g * 8];

    f32x4 acc[4][4];   // acc[mt][nt]: rows j = mt*16+g*4+r, cols i = nt*16+ln
#pragma unroll
    for (int i = 0; i < 4; i++)
#pragma unroll
        for (int j = 0; j < 4; j++) acc[i][j] = {0.f, 0.f, 0.f, 0.f};

#pragma unroll
    for (int mt = 0; mt < 4; mt++)
#pragma unroll
        for (int nt = 0; nt < 4; nt++)
            acc[mt][nt] = __builtin_amdgcn_mfma_f32_16x16x32_bf16(
                kf[mt], qf[nt], acc[mt][nt], 0, 0, 0);

    // bias + mask: cwb[w][h][i][j], j = mt*16+g*4+r consecutive -> float4
    const float* cw = cwb + (size_t)(w * 16 + h) * 4096;
#pragma unroll
    for (int nt = 0; nt < 4; nt++) {
        const int i = nt * 16 + ln;
#pragma unroll
        for (int mt = 0; mt < 4; mt++) {
            const float4 bm = *(const float4*)&cw[i * 64 + mt * 16 + (g << 2)];
            acc[mt][nt][0] += bm.x; acc[mt][nt][1] += bm.y;
            acc[mt][nt][2] += bm.z; acc[mt][nt][3] += bm.w;
        }
    }

    // softmax over j (per column i), then P -> LDS bf16 [i][j] swizzled
#pragma unroll
    for (int nt = 0; nt < 4; nt++) {
        float mx = acc[0][nt][0];
#pragma unroll
        for (int mt = 0; mt < 4; mt++)
#pragma unroll
            for (int r = 0; r < 4; r++) mx = fmaxf(mx, acc[mt][nt][r]);
        mx = fmaxf(mx, __shfl_xor(mx, 16));
        mx = fmaxf(mx, __shfl_xor(mx, 32));
        float sum = 0.f;
#pragma unroll
        for (int mt = 0; mt < 4; mt++)
#pragma unroll
            for (int r = 0; r < 4; r++) {
                const float p = __expf(acc[mt][nt][r] - mx);
                acc[mt][nt][r] = p;
                sum += p;
            }
        sum += __shfl_xor(sum, 16);
        sum += __shfl_xor(sum, 32);
        const float rs = 1.0f / sum;
        const int i = nt * 16 + ln;
#pragma unroll
        for (int mt = 0; mt < 4; mt++) {
            short4_t hq;
#pragma unroll
            for (int r = 0; r < 4; r++) hq[r] = (short)f2bf(acc[mt][nt][r] * rs);
            const int idx = (i * 64 + mt * 16 + (g << 2)) ^ ((i & 7) << 3);
            *(short4_t*)&P[idx] = hq;
        }
    }
    __syncthreads();

    // O^T[d][i] = sum_j V^T[d][j] P[i][j]
    f32x4 oacc[2][4];
#pragma unroll
    for (int i = 0; i < 2; i++)
#pragma unroll
        for (int j = 0; j < 4; j++) oacc[i][j] = {0.f, 0.f, 0.f, 0.f};

#pragma unroll
    for (int ks = 0; ks < 2; ks++) {
        bf16x8 vf[2], pf[4];
#pragma unroll
        for (int mt = 0; mt < 2; mt++)
            vf[mt] = *(const bf16x8*)&vt[base + (mt * 16 + ln) * 64 + ks * 32 + g * 8];
#pragma unroll
        for (int nt = 0; nt < 4; nt++) {
            const int i = nt * 16 + ln;
            pf[nt] = *(const bf16x8*)&P[(i * 64 + ks * 32 + g * 8) ^ ((i & 7) << 3)];
        }
#pragma unroll
        for (int mt = 0; mt < 2; mt++)
#pragma unroll
            for (int nt = 0; nt < 4; nt++)
                oacc[mt][nt] = __builtin_amdgcn_mfma_f32_16x16x32_bf16(
                    vf[mt], pf[nt], oacc[mt][nt], 0, 0, 0);
    }

    // store x[b][i][h*32+d], d = mt*16+g*4+r consecutive -> packed 8B
#pragma unroll
    for (int mt = 0; mt < 2; mt++) {
#pragma unroll
        for (int nt = 0; nt < 4; nt++) {
            const int i = nt * 16 + ln, d0 = mt * 16 + (g << 2);
            short4_t hq;
#pragma unroll
            for (int r = 0; r < 4; r++) hq[r] = (short)f2bf(oacc[mt][nt][r]);
            *(short4_t*)&xout[((size_t)b * 64 + i) * 512 + h * 32 + d0] = hq;
        }
    }
}

// ---------------------------------------------------------------------------
extern "C" void kernel_launch(void* const* d_in, const int* in_sizes, int n_in,
                              void* d_out, int out_size, void* d_ws, size_t ws_size,
                              hipStream_t stream) {
    const float* q    = (const float*)d_in[0];
    const float* k    = (const float*)d_in[1];
    const float* v    = (const float*)d_in[2];
    const float* mask = (const float*)d_in[3];
    const float* Wq   = (const float*)d_in[4];
    const float* bq   = (const float*)d_in[5];
    const float* Wk   = (const float*)d_in[6];
    const float* bk   = (const float*)d_in[7];
    const float* Wv   = (const float*)d_in[8];
    const float* bv   = (const float*)d_in[9];
    const float* Wp   = (const float*)d_in[10];
    const float* bp   = (const float*)d_in[11];
    const float* bias_table = (const float*)d_in[12];
    float* out = (float*)d_out;

    // workspace layout (bytes): qh 64MB | kh 64MB | vt 64MB | x 64MB | cwb 16MB
    char* ws = (char*)d_ws;
    u16*   qh  = (u16*)(ws);
    u16*   kh  = (u16*)(ws + 67108864);
    u16*   vt  = (u16*)(ws + 134217728);
    u16*   xb  = (u16*)(ws + 201326592);
    float* cwb = (float*)(ws + 268435456);   // total 285,212,672 B

    cwb_kernel<<<1024, 256, 0, stream>>>(bias_table, mask, cwb);

    gemm_k<0, 0><<<dim3(4, 512), 256, 0, stream>>>((const void*)q, Wq, bq, SCALE_Q, (void*)qh);
    gemm_k<0, 0><<<dim3(4, 512), 256, 0, stream>>>((const void*)k, Wk, bk, 1.0f,    (void*)kh);
    gemm_k<0, 1><<<dim3(4, 512), 256, 0, stream>>>((const void*)v, Wv, bv, 1.0f,    (void*)vt);

    attn_kernel<<<16384, 64, 0, stream>>>(qh, kh, vt, cwb, xb);

    gemm_k<1, 2><<<dim3(4, 512), 256, 0, stream>>>((const void*)xb, Wp, bp, 1.0f, (void*)out);
}

// Round 2
// 459.196 us; speedup vs baseline: 1.4964x; 1.4964x over previous
//
#include <hip/hip_runtime.h>
#include <hip/hip_bf16.h>

typedef __attribute__((ext_vector_type(4))) float  f32x4;
typedef __attribute__((ext_vector_type(8))) short  bf16x8;
typedef __attribute__((ext_vector_type(4))) short  short4_t;
typedef unsigned short u16;

#define SCALE_Q 0.17677669529663687f   // 32^-0.5

__device__ __forceinline__ u16 f2bf(float f) {
    union { float f; unsigned u; } v; v.f = f;
    unsigned u = v.u;
    return (u16)((u + 0x7FFFu + ((u >> 16) & 1u)) >> 16);  // RNE
}

__device__ __forceinline__ void load_lds16(const void* g, void* l) {
    __builtin_amdgcn_global_load_lds(
        (const __attribute__((address_space(1))) void*)g,
        (__attribute__((address_space(3))) void*)l, 16, 0, 0);
}

// ---------------------------------------------------------------------------
// fp32 -> bf16 convert, 8 elems/thread (read 32B, write 16B)
// ---------------------------------------------------------------------------
__global__ __launch_bounds__(256) void cvt_kernel(
        const float* __restrict__ s, u16* __restrict__ d, int n8)
{
    const int i = blockIdx.x * 256 + threadIdx.x;
    if (i >= n8) return;
    const float4* sp = (const float4*)s + (size_t)i * 2;
    const float4 a = sp[0], b = sp[1];
    bf16x8 o;
    o[0] = (short)f2bf(a.x); o[1] = (short)f2bf(a.y);
    o[2] = (short)f2bf(a.z); o[3] = (short)f2bf(a.w);
    o[4] = (short)f2bf(b.x); o[5] = (short)f2bf(b.y);
    o[6] = (short)f2bf(b.z); o[7] = (short)f2bf(b.w);
    *((bf16x8*)d + i) = o;
}

// ---------------------------------------------------------------------------
// cwb[w][h][i][j] = bias_table[REL_IDX[i][j]][h] + mask[w][i][j]   (fp32)
// ---------------------------------------------------------------------------
__global__ __launch_bounds__(256) void cwb_kernel(
        const float* __restrict__ bias_table,   // [225][16]
        const float* __restrict__ mask,         // [64][64][64]
        float* __restrict__ cwb)                // [64][16][64][64]
{
    const int wh = blockIdx.x;          // w*16 + h
    const int w = wh >> 4, h = wh & 15;
    for (int e = threadIdx.x; e < 4096; e += 256) {
        const int i = e >> 6, j = e & 63;
        const int rel = ((i >> 3) - (j >> 3) + 7) * 15 + (i & 7) - (j & 7) + 7;
        cwb[(size_t)wh * 4096 + e] = bias_table[rel * 16 + h] + mask[(size_t)w * 4096 + e];
    }
}

// ---------------------------------------------------------------------------
// GEMM (m97-structure): C[65536,512] = A[65536,512]b16 @ W[512,512]b16^T
//   + bias, * scale.  128x128 tile, BK=64, 4 waves (2x2), 16x16x32 bf16 MFMA.
// Staging: global_load_lds 16B, linear LDS dest + pre-swizzled global source
// so LDS holds the XOR-swizzled tile; ds_read_b128 uses the same XOR.
// Swizzle: 16B-block cb of row r lives at block (cb ^ (r&7))  (byte ^ (r&7)<<4).
// OMODE: 0 = bf16 out [b][h][t][d]; 1 = bf16 out [b][h][d][t]; 2 = fp32 [m][n]
// ---------------------------------------------------------------------------
template<int OMODE>
__global__ __launch_bounds__(256) void gemm_bf16(
        const u16* __restrict__ A, const u16* __restrict__ Wb,
        const float* __restrict__ bias, float scale, void* __restrict__ outp)
{
    __shared__ __align__(16) u16 As[8192];   // [128][64] swizzled
    __shared__ __align__(16) u16 Bs[8192];

    const int t  = threadIdx.x;
    const int m0 = blockIdx.y << 7;
    const int n0 = blockIdx.x << 7;
    const int lane = t & 63, wv = t >> 6;
    const int g = lane >> 4, ln = lane & 15;
    const int wr = wv >> 1, wc = wv & 1;
    const int wbase = wv << 6;               // wave's first 16B-block per round

    f32x4 acc[4][4];
#pragma unroll
    for (int i = 0; i < 4; i++)
#pragma unroll
        for (int j = 0; j < 4; j++) acc[i][j] = {0.f, 0.f, 0.f, 0.f};

    const u16* Abase = A  + (size_t)m0 * 512;
    const u16* Bbase = Wb + (size_t)n0 * 512;

    for (int k0 = 0; k0 < 512; k0 += 64) {
#pragma unroll
        for (int c = 0; c < 4; c++) {
            const int bi  = (c << 8) + wbase + lane;      // 16B-block 0..1023
            const int row = bi >> 3;
            const int cbs = (bi & 7) ^ (row & 7);         // pre-swizzled src block
            const size_t go = (size_t)row * 512 + k0 + (cbs << 3);
            u16* ldst = (c & 1) ? &Bs[(((c >> 1) << 9) + (wbase << 1)) << 3]
                                : &As[(((c >> 1) << 9) + (wbase << 1)) << 3];
            (void)ldst; // (see explicit calls below)
            load_lds16(Abase + go, &As[((c << 8) + wbase) << 3]);
            load_lds16(Bbase + go, &Bs[((c << 8) + wbase) << 3]);
        }
        __syncthreads();   // compiler drains vmcnt(0) here
#pragma unroll
        for (int ks = 0; ks < 2; ks++) {
            bf16x8 af[4], bfr[4];
#pragma unroll
            for (int mt = 0; mt < 4; mt++) {
                const int row = (wr << 6) + (mt << 4) + ln;
                af[mt] = *(const bf16x8*)&As[(row << 6) + ((((ks << 2) + g) ^ (row & 7)) << 3)];
            }
#pragma unroll
            for (int nt = 0; nt < 4; nt++) {
                const int row = (wc << 6) + (nt << 4) + ln;
                bfr[nt] = *(const bf16x8*)&Bs[(row << 6) + ((((ks << 2) + g) ^ (row & 7)) << 3)];
            }
#pragma unroll
            for (int mt = 0; mt < 4; mt++)
#pragma unroll
                for (int nt = 0; nt < 4; nt++)
                    acc[mt][nt] = __builtin_amdgcn_mfma_f32_16x16x32_bf16(
                        af[mt], bfr[nt], acc[mt][nt], 0, 0, 0);
        }
        __syncthreads();
    }

    // ---- epilogue: bias, scale, store ----
#pragma unroll
    for (int mt = 0; mt < 4; mt++) {
#pragma unroll
        for (int nt = 0; nt < 4; nt++) {
            const int n = n0 + (wc << 6) + (nt << 4) + ln;
            const float bv = bias[n];
            const int mbase = m0 + (wr << 6) + (mt << 4) + (g << 2);
            if (OMODE == 0) {
#pragma unroll
                for (int r = 0; r < 4; r++) {
                    const int m = mbase + r;
                    const int b = m >> 6, tt = m & 63, hh = n >> 5, d = n & 31;
                    ((u16*)outp)[((size_t)(b * 16 + hh) * 64 + tt) * 32 + d] =
                        f2bf((acc[mt][nt][r] + bv) * scale);
                }
            } else if (OMODE == 1) {
                short4_t hq;
#pragma unroll
                for (int r = 0; r < 4; r++) hq[r] = (short)f2bf((acc[mt][nt][r] + bv) * scale);
                const int b = mbase >> 6, tt = mbase & 63, hh = n >> 5, d = n & 31;
                *(short4_t*)&((u16*)outp)[((size_t)(b * 16 + hh) * 32 + d) * 64 + tt] = hq;
            } else {
#pragma unroll
                for (int r = 0; r < 4; r++) {
                    const int m = mbase + r;
                    ((float*)outp)[(size_t)m * 512 + n] = (acc[mt][nt][r] + bv) * scale;
                }
            }
        }
    }
}

// ---------------------------------------------------------------------------
// Attention: one wave per (b,h). S^T = K·Q^T via mfma(K,Q); softmax over j via
// local reduce + shfl_xor 16/32; P -> LDS bf16 [i][j] XOR-swizzled; O^T = V^T·P.
// qh,kh: [b][h][t][d] bf16 ; vt: [b][h][d][t] bf16 ; x out: [b][t][h*32+d] bf16
// ---------------------------------------------------------------------------
__global__ __launch_bounds__(64) void attn_kernel(
        const u16* __restrict__ qh, const u16* __restrict__ kh,
        const u16* __restrict__ vt, const float* __restrict__ cwb,
        u16* __restrict__ xout)
{
    __shared__ __align__(16) u16 P[4096];

    const int bid = blockIdx.x;                 // b*16 + h
    const int b = bid >> 4, h = bid & 15, w = b & 63;
    const int lane = threadIdx.x, g = lane >> 4, ln = lane & 15;
    const size_t base = (size_t)bid * 2048;

    bf16x8 kf[4], qf[4];
#pragma unroll
    for (int mt = 0; mt < 4; mt++)
        kf[mt] = *(const bf16x8*)&kh[base + (mt * 16 + ln) * 32 + g * 8];
#pragma unroll
    for (int nt = 0; nt < 4; nt++)
        qf[nt] = *(const bf16x8*)&qh[base + (nt * 16 + ln) * 32 + g * 8];

    f32x4 acc[4][4];   // acc[mt][nt]: rows j = mt*16+g*4+r, cols i = nt*16+ln
#pragma unroll
    for (int i = 0; i < 4; i++)
#pragma unroll
        for (int j = 0; j < 4; j++) acc[i][j] = {0.f, 0.f, 0.f, 0.f};

#pragma unroll
    for (int mt = 0; mt < 4; mt++)
#pragma unroll
        for (int nt = 0; nt < 4; nt++)
            acc[mt][nt] = __builtin_amdgcn_mfma_f32_16x16x32_bf16(
                kf[mt], qf[nt], acc[mt][nt], 0, 0, 0);

    const float* cw = cwb + (size_t)(w * 16 + h) * 4096;
#pragma unroll
    for (int nt = 0; nt < 4; nt++) {
        const int i = nt * 16 + ln;
#pragma unroll
        for (int mt = 0; mt < 4; mt++) {
            const float4 bm = *(const float4*)&cw[i * 64 + mt * 16 + (g << 2)];
            acc[mt][nt][0] += bm.x; acc[mt][nt][1] += bm.y;
            acc[mt][nt][2] += bm.z; acc[mt][nt][3] += bm.w;
        }
    }

#pragma unroll
    for (int nt = 0; nt < 4; nt++) {
        float mx = acc[0][nt][0];
#pragma unroll
        for (int mt = 0; mt < 4; mt++)
#pragma unroll
            for (int r = 0; r < 4; r++) mx = fmaxf(mx, acc[mt][nt][r]);
        mx = fmaxf(mx, __shfl_xor(mx, 16));
        mx = fmaxf(mx, __shfl_xor(mx, 32));
        float sum = 0.f;
#pragma unroll
        for (int mt = 0; mt < 4; mt++)
#pragma unroll
            for (int r = 0; r < 4; r++) {
                const float p = __expf(acc[mt][nt][r] - mx);
                acc[mt][nt][r] = p;
                sum += p;
            }
        sum += __shfl_xor(sum, 16);
        sum += __shfl_xor(sum, 32);
        const float rs = 1.0f / sum;
        const int i = nt * 16 + ln;
#pragma unroll
        for (int mt = 0; mt < 4; mt++) {
            short4_t hq;
#pragma unroll
            for (int r = 0; r < 4; r++) hq[r] = (short)f2bf(acc[mt][nt][r] * rs);
            const int idx = (i * 64 + mt * 16 + (g << 2)) ^ ((i & 7) << 3);
            *(short4_t*)&P[idx] = hq;
        }
    }
    __syncthreads();

    f32x4 oacc[2][4];
#pragma unroll
    for (int i = 0; i < 2; i++)
#pragma unroll
        for (int j = 0; j < 4; j++) oacc[i][j] = {0.f, 0.f, 0.f, 0.f};

#pragma unroll
    for (int ks = 0; ks < 2; ks++) {
        bf16x8 vf[2], pf[4];
#pragma unroll
        for (int mt = 0; mt < 2; mt++)
            vf[mt] = *(const bf16x8*)&vt[base + (mt * 16 + ln) * 64 + ks * 32 + g * 8];
#pragma unroll
        for (int nt = 0; nt < 4; nt++) {
            const int i = nt * 16 + ln;
            pf[nt] = *(const bf16x8*)&P[(i * 64 + ks * 32 + g * 8) ^ ((i & 7) << 3)];
        }
#pragma unroll
        for (int mt = 0; mt < 2; mt++)
#pragma unroll
            for (int nt = 0; nt < 4; nt++)
                oacc[mt][nt] = __builtin_amdgcn_mfma_f32_16x16x32_bf16(
                    vf[mt], pf[nt], oacc[mt][nt], 0, 0, 0);
    }

#pragma unroll
    for (int mt = 0; mt < 2; mt++) {
#pragma unroll
        for (int nt = 0; nt < 4; nt++) {
            const int i = nt * 16 + ln, d0 = mt * 16 + (g << 2);
            short4_t hq;
#pragma unroll
            for (int r = 0; r < 4; r++) hq[r] = (short)f2bf(oacc[mt][nt][r]);
            *(short4_t*)&xout[((size_t)b * 64 + i) * 512 + h * 32 + d0] = hq;
        }
    }
}

// ---------------------------------------------------------------------------
extern "C" void kernel_launch(void* const* d_in, const int* in_sizes, int n_in,
                              void* d_out, int out_size, void* d_ws, size_t ws_size,
                              hipStream_t stream) {
    const float* q    = (const float*)d_in[0];
    const float* k    = (const float*)d_in[1];
    const float* v    = (const float*)d_in[2];
    const float* mask = (const float*)d_in[3];
    const float* Wq   = (const float*)d_in[4];
    const float* bq   = (const float*)d_in[5];
    const float* Wk   = (const float*)d_in[6];
    const float* bk   = (const float*)d_in[7];
    const float* Wv   = (const float*)d_in[8];
    const float* bv   = (const float*)d_in[9];
    const float* Wp   = (const float*)d_in[10];
    const float* bp   = (const float*)d_in[11];
    const float* bias_table = (const float*)d_in[12];
    float* out = (float*)d_out;

    // ws layout (bytes):
    //   t0  @ 0         (67,108,864)  reused: q_bf16 / k_bf16 / v_bf16 / x_bf16
    //   qh  @ 64MB, kh @ 128MB, vt @ 192MB (67,108,864 each, bf16)
    //   cwb @ 256MB     (16,777,216)
    //   wqb/wkb/wvb/wpb @ 272MB (524,288 each)
    char* ws = (char*)d_ws;
    u16*   t0  = (u16*)(ws);
    u16*   qh  = (u16*)(ws + 67108864);
    u16*   kh  = (u16*)(ws + 134217728);
    u16*   vt  = (u16*)(ws + 201326592);
    float* cwb = (float*)(ws + 268435456);
    u16*   wqb = (u16*)(ws + 285212672);
    u16*   wkb = (u16*)(ws + 285736960);
    u16*   wvb = (u16*)(ws + 286261248);
    u16*   wpb = (u16*)(ws + 286785536);

    const int n8_act = (1024 * 64 * 512) / 8;   // 4,194,304
    const int n8_w   = (512 * 512) / 8;         // 32,768

    cwb_kernel<<<1024, 256, 0, stream>>>(bias_table, mask, cwb);
    cvt_kernel<<<n8_w / 256, 256, 0, stream>>>(Wq, wqb, n8_w);
    cvt_kernel<<<n8_w / 256, 256, 0, stream>>>(Wk, wkb, n8_w);
    cvt_kernel<<<n8_w / 256, 256, 0, stream>>>(Wv, wvb, n8_w);
    cvt_kernel<<<n8_w / 256, 256, 0, stream>>>(Wp, wpb, n8_w);

    cvt_kernel<<<n8_act / 256, 256, 0, stream>>>(q, t0, n8_act);
    gemm_bf16<0><<<dim3(4, 512), 256, 0, stream>>>(t0, wqb, bq, SCALE_Q, (void*)qh);

    cvt_kernel<<<n8_act / 256, 256, 0, stream>>>(k, t0, n8_act);
    gemm_bf16<0><<<dim3(4, 512), 256, 0, stream>>>(t0, wkb, bk, 1.0f, (void*)kh);

    cvt_kernel<<<n8_act / 256, 256, 0, stream>>>(v, t0, n8_act);
    gemm_bf16<1><<<dim3(4, 512), 256, 0, stream>>>(t0, wvb, bv, 1.0f, (void*)vt);

    attn_kernel<<<16384, 64, 0, stream>>>(qh, kh, vt, cwb, t0);

    gemm_bf16<2><<<dim3(4, 512), 256, 0, stream>>>(t0, wpb, bp, 1.0f, (void*)out);
}

// Round 3
// 417.683 us; speedup vs baseline: 1.6451x; 1.0994x over previous
//
#include <hip/hip_runtime.h>
#include <hip/hip_bf16.h>

typedef __attribute__((ext_vector_type(4))) float  f32x4;
typedef __attribute__((ext_vector_type(8))) short  bf16x8;
typedef __attribute__((ext_vector_type(4))) short  short4_t;
typedef unsigned short u16;

#define SCALE_Q 0.17677669529663687f   // 32^-0.5

// native RNE float->bf16 (compiler packs pairs into v_cvt_pk_bf16_f32)
__device__ __forceinline__ short bfc(float f) {
    __bf16 b = (__bf16)f;
    union { __bf16 b; short s; } u; u.b = b; return u.s;
}

__device__ __forceinline__ bf16x8 pack8(f32x4 a, f32x4 b) {
    bf16x8 o;
    o[0] = bfc(a[0]); o[1] = bfc(a[1]); o[2] = bfc(a[2]); o[3] = bfc(a[3]);
    o[4] = bfc(b[0]); o[5] = bfc(b[1]); o[6] = bfc(b[2]); o[7] = bfc(b[3]);
    return o;
}

__device__ __forceinline__ void load_lds16(const void* g, void* l) {
    __builtin_amdgcn_global_load_lds(
        (const __attribute__((address_space(1))) void*)g,
        (__attribute__((address_space(3))) void*)l, 16, 0, 0);
}

// ---------------------------------------------------------------------------
// fp32 -> bf16 convert (weights only), 8 elems/thread
// ---------------------------------------------------------------------------
__global__ __launch_bounds__(256) void cvt_kernel(
        const float* __restrict__ s, u16* __restrict__ d, int n8)
{
    const int i = blockIdx.x * 256 + threadIdx.x;
    if (i >= n8) return;
    const float4* sp = (const float4*)s + (size_t)i * 2;
    const float4 a = sp[0], b = sp[1];
    bf16x8 o;
    o[0] = bfc(a.x); o[1] = bfc(a.y); o[2] = bfc(a.z); o[3] = bfc(a.w);
    o[4] = bfc(b.x); o[5] = bfc(b.y); o[6] = bfc(b.z); o[7] = bfc(b.w);
    *((bf16x8*)d + i) = o;
}

// ---------------------------------------------------------------------------
// cwb[w][h][i][j] = bias_table[REL_IDX[i][j]][h] + mask[w][i][j]   (fp32)
// ---------------------------------------------------------------------------
__global__ __launch_bounds__(256) void cwb_kernel(
        const float* __restrict__ bias_table,   // [225][16]
        const float* __restrict__ mask,         // [64][64][64]
        float* __restrict__ cwb)                // [64][16][64][64]
{
    const int wh = blockIdx.x;          // w*16 + h
    const int w = wh >> 4, h = wh & 15;
    for (int e = threadIdx.x; e < 4096; e += 256) {
        const int i = e >> 6, j = e & 63;
        const int rel = ((i >> 3) - (j >> 3) + 7) * 15 + (i & 7) - (j & 7) + 7;
        cwb[(size_t)wh * 4096 + e] = bias_table[rel * 16 + h] + mask[(size_t)w * 4096 + e];
    }
}

// ---------------------------------------------------------------------------
// GEMM: C[65536,512] = A[65536,512] @ W[512,512]b16^T + bias, * scale.
// 128x128 tile, BK=64, 4 waves (2x2), 16x16x32 bf16 MFMA, global_load_lds 16B
// staging with pre-swizzled global source (LDS dest stays linear).
// AFP32: 1 = A fp32 (staged raw, converted in-register after ds_read_b128)
//        0 = A bf16
// Swizzle: 16B-block cb of row r lives at physical block (cb ^ (r&7)).
// OMODE: 0 = bf16 out [b][h][t][d]; 1 = bf16 out [b][h][d][t]; 2 = fp32 [m][n]
// XCD-aware block swizzle: nwg=2048, 256 per XCD chunk.
// ---------------------------------------------------------------------------
template<int AFP32, int OMODE>
__global__ __launch_bounds__(256) void gemm_k(
        const void* __restrict__ Aptr, const u16* __restrict__ Wb,
        const float* __restrict__ bias, float scale, void* __restrict__ outp)
{
    __shared__ __align__(16) unsigned char Asb[AFP32 ? 32768 : 16384];
    __shared__ __align__(16) u16 Bs[8192];   // 16 KB

    // XCD swizzle: 2048 wgs, 8 XCDs, 256 contiguous per XCD
    const int wg = (blockIdx.x & 7) * 256 + (blockIdx.x >> 3);
    const int m0 = (wg >> 2) << 7;
    const int n0 = (wg & 3) << 7;

    const int t = threadIdx.x;
    const int lane = t & 63, wv = t >> 6;
    const int g = lane >> 4, ln = lane & 15;
    const int wr = wv >> 1, wc = wv & 1;

    f32x4 acc[4][4];
#pragma unroll
    for (int i = 0; i < 4; i++)
#pragma unroll
        for (int j = 0; j < 4; j++) acc[i][j] = {0.f, 0.f, 0.f, 0.f};

    for (int k0 = 0; k0 < 512; k0 += 64) {
        // ---- stage A ----
        if (AFP32) {
            const float* Ab = (const float*)Aptr + (size_t)m0 * 512;
#pragma unroll
            for (int c = 0; c < 8; c++) {
                const int bi  = (c << 8) + (wv << 6) + lane;   // 16B-block 0..2047
                const int row = bi >> 4;
                const int col = ((bi & 15) ^ (row & 7)) << 2;  // fp32 col (pre-swizzled src)
                load_lds16(Ab + (size_t)row * 512 + k0 + col,
                           &Asb[((c << 8) + (wv << 6)) << 4]);
            }
        } else {
            const u16* Ab = (const u16*)Aptr + (size_t)m0 * 512;
#pragma unroll
            for (int c = 0; c < 4; c++) {
                const int bi  = (c << 8) + (wv << 6) + lane;   // 16B-block 0..1023
                const int row = bi >> 3;
                const int col = ((bi & 7) ^ (row & 7)) << 3;   // u16 col
                load_lds16(Ab + (size_t)row * 512 + k0 + col,
                           &Asb[((c << 8) + (wv << 6)) << 4]);
            }
        }
        // ---- stage B ----
        {
            const u16* Bb = Wb + (size_t)n0 * 512;
#pragma unroll
            for (int c = 0; c < 4; c++) {
                const int bi  = (c << 8) + (wv << 6) + lane;
                const int row = bi >> 3;
                const int col = ((bi & 7) ^ (row & 7)) << 3;
                load_lds16(Bb + (size_t)row * 512 + k0 + col,
                           &Bs[((c << 8) + (wv << 6)) << 3]);
            }
        }
        __syncthreads();   // drains vmcnt(0)

#pragma unroll
        for (int ks = 0; ks < 2; ks++) {
            bf16x8 af[4], bfr[4];
#pragma unroll
            for (int mt = 0; mt < 4; mt++) {
                const int row = (wr << 6) + (mt << 4) + ln;
                if (AFP32) {
                    const int lb = (ks << 3) + (g << 1);
                    const f32x4 lo = *(const f32x4*)&Asb[row * 256 + (((lb    ) ^ (row & 7)) << 4)];
                    const f32x4 hi = *(const f32x4*)&Asb[row * 256 + (((lb + 1) ^ (row & 7)) << 4)];
                    af[mt] = pack8(lo, hi);
                } else {
                    af[mt] = *(const bf16x8*)&Asb[(row << 7) + ((((ks << 2) + g) ^ (row & 7)) << 4)];
                }
            }
#pragma unroll
            for (int nt = 0; nt < 4; nt++) {
                const int row = (wc << 6) + (nt << 4) + ln;
                bfr[nt] = *(const bf16x8*)&Bs[(row << 6) + ((((ks << 2) + g) ^ (row & 7)) << 3)];
            }
#pragma unroll
            for (int mt = 0; mt < 4; mt++)
#pragma unroll
                for (int nt = 0; nt < 4; nt++)
                    acc[mt][nt] = __builtin_amdgcn_mfma_f32_16x16x32_bf16(
                        af[mt], bfr[nt], acc[mt][nt], 0, 0, 0);
        }
        __syncthreads();
    }

    // ---- epilogue: bias, scale, store ----
#pragma unroll
    for (int mt = 0; mt < 4; mt++) {
#pragma unroll
        for (int nt = 0; nt < 4; nt++) {
            const int n = n0 + (wc << 6) + (nt << 4) + ln;
            const float bv = bias[n];
            const int mbase = m0 + (wr << 6) + (mt << 4) + (g << 2);
            if (OMODE == 0) {
#pragma unroll
                for (int r = 0; r < 4; r++) {
                    const int m = mbase + r;
                    const int b = m >> 6, tt = m & 63, hh = n >> 5, d = n & 31;
                    ((u16*)outp)[((size_t)(b * 16 + hh) * 64 + tt) * 32 + d] =
                        (u16)bfc((acc[mt][nt][r] + bv) * scale);
                }
            } else if (OMODE == 1) {
                short4_t hq;
#pragma unroll
                for (int r = 0; r < 4; r++) hq[r] = bfc((acc[mt][nt][r] + bv) * scale);
                const int b = mbase >> 6, tt = mbase & 63, hh = n >> 5, d = n & 31;
                *(short4_t*)&((u16*)outp)[((size_t)(b * 16 + hh) * 32 + d) * 64 + tt] = hq;
            } else {
#pragma unroll
                for (int r = 0; r < 4; r++) {
                    const int m = mbase + r;
                    ((float*)outp)[(size_t)m * 512 + n] = (acc[mt][nt][r] + bv) * scale;
                }
            }
        }
    }
}

// ---------------------------------------------------------------------------
// Attention: 4 waves/block, one (b,h) per wave. S^T = K·Q^T via mfma(K,Q);
// softmax over j = local reduce + shfl_xor 16/32; P -> private LDS region
// bf16 [i][j] XOR-swizzled; O^T = V^T·P.
// qh,kh: [b][h][t][d] bf16 ; vt: [b][h][d][t] bf16 ; x out: [b][t][h*32+d] bf16
// ---------------------------------------------------------------------------
__global__ __launch_bounds__(256) void attn_kernel(
        const u16* __restrict__ qh, const u16* __restrict__ kh,
        const u16* __restrict__ vt, const float* __restrict__ cwb,
        u16* __restrict__ xout)
{
    __shared__ __align__(16) u16 P[16384];   // 4 waves x 8 KB

    const int wv = threadIdx.x >> 6;
    const int bid = (blockIdx.x << 2) + wv;     // b*16 + h
    const int b = bid >> 4, h = bid & 15, w = b & 63;
    const int lane = threadIdx.x & 63, g = lane >> 4, ln = lane & 15;
    const size_t base = (size_t)bid * 2048;
    u16* Pw = &P[wv << 12];

    bf16x8 kf[4], qf[4];
#pragma unroll
    for (int mt = 0; mt < 4; mt++)
        kf[mt] = *(const bf16x8*)&kh[base + (mt * 16 + ln) * 32 + g * 8];
#pragma unroll
    for (int nt = 0; nt < 4; nt++)
        qf[nt] = *(const bf16x8*)&qh[base + (nt * 16 + ln) * 32 + g * 8];

    f32x4 acc[4][4];   // acc[mt][nt]: rows j = mt*16+g*4+r, cols i = nt*16+ln
#pragma unroll
    for (int i = 0; i < 4; i++)
#pragma unroll
        for (int j = 0; j < 4; j++) acc[i][j] = {0.f, 0.f, 0.f, 0.f};

#pragma unroll
    for (int mt = 0; mt < 4; mt++)
#pragma unroll
        for (int nt = 0; nt < 4; nt++)
            acc[mt][nt] = __builtin_amdgcn_mfma_f32_16x16x32_bf16(
                kf[mt], qf[nt], acc[mt][nt], 0, 0, 0);

    const float* cw = cwb + (size_t)(w * 16 + h) * 4096;
#pragma unroll
    for (int nt = 0; nt < 4; nt++) {
        const int i = nt * 16 + ln;
#pragma unroll
        for (int mt = 0; mt < 4; mt++) {
            const float4 bm = *(const float4*)&cw[i * 64 + mt * 16 + (g << 2)];
            acc[mt][nt][0] += bm.x; acc[mt][nt][1] += bm.y;
            acc[mt][nt][2] += bm.z; acc[mt][nt][3] += bm.w;
        }
    }

#pragma unroll
    for (int nt = 0; nt < 4; nt++) {
        float mx = acc[0][nt][0];
#pragma unroll
        for (int mt = 0; mt < 4; mt++)
#pragma unroll
            for (int r = 0; r < 4; r++) mx = fmaxf(mx, acc[mt][nt][r]);
        mx = fmaxf(mx, __shfl_xor(mx, 16));
        mx = fmaxf(mx, __shfl_xor(mx, 32));
        float sum = 0.f;
#pragma unroll
        for (int mt = 0; mt < 4; mt++)
#pragma unroll
            for (int r = 0; r < 4; r++) {
                const float p = __expf(acc[mt][nt][r] - mx);
                acc[mt][nt][r] = p;
                sum += p;
            }
        sum += __shfl_xor(sum, 16);
        sum += __shfl_xor(sum, 32);
        const float rs = 1.0f / sum;
        const int i = nt * 16 + ln;
#pragma unroll
        for (int mt = 0; mt < 4; mt++) {
            short4_t hq;
#pragma unroll
            for (int r = 0; r < 4; r++) hq[r] = bfc(acc[mt][nt][r] * rs);
            const int idx = (i * 64 + mt * 16 + (g << 2)) ^ ((i & 7) << 3);
            *(short4_t*)&Pw[idx] = hq;
        }
    }
    __syncthreads();

    f32x4 oacc[2][4];
#pragma unroll
    for (int i = 0; i < 2; i++)
#pragma unroll
        for (int j = 0; j < 4; j++) oacc[i][j] = {0.f, 0.f, 0.f, 0.f};

#pragma unroll
    for (int ks = 0; ks < 2; ks++) {
        bf16x8 vf[2], pf[4];
#pragma unroll
        for (int mt = 0; mt < 2; mt++)
            vf[mt] = *(const bf16x8*)&vt[base + (mt * 16 + ln) * 64 + ks * 32 + g * 8];
#pragma unroll
        for (int nt = 0; nt < 4; nt++) {
            const int i = nt * 16 + ln;
            pf[nt] = *(const bf16x8*)&Pw[(i * 64 + ks * 32 + g * 8) ^ ((i & 7) << 3)];
        }
#pragma unroll
        for (int mt = 0; mt < 2; mt++)
#pragma unroll
            for (int nt = 0; nt < 4; nt++)
                oacc[mt][nt] = __builtin_amdgcn_mfma_f32_16x16x32_bf16(
                    vf[mt], pf[nt], oacc[mt][nt], 0, 0, 0);
    }

#pragma unroll
    for (int mt = 0; mt < 2; mt++) {
#pragma unroll
        for (int nt = 0; nt < 4; nt++) {
            const int i = nt * 16 + ln, d0 = mt * 16 + (g << 2);
            short4_t hq;
#pragma unroll
            for (int r = 0; r < 4; r++) hq[r] = bfc(oacc[mt][nt][r]);
            *(short4_t*)&xout[((size_t)b * 64 + i) * 512 + h * 32 + d0] = hq;
        }
    }
}

// ---------------------------------------------------------------------------
extern "C" void kernel_launch(void* const* d_in, const int* in_sizes, int n_in,
                              void* d_out, int out_size, void* d_ws, size_t ws_size,
                              hipStream_t stream) {
    const float* q    = (const float*)d_in[0];
    const float* k    = (const float*)d_in[1];
    const float* v    = (const float*)d_in[2];
    const float* mask = (const float*)d_in[3];
    const float* Wq   = (const float*)d_in[4];
    const float* bq   = (const float*)d_in[5];
    const float* Wk   = (const float*)d_in[6];
    const float* bk   = (const float*)d_in[7];
    const float* Wv   = (const float*)d_in[8];
    const float* bv   = (const float*)d_in[9];
    const float* Wp   = (const float*)d_in[10];
    const float* bp   = (const float*)d_in[11];
    const float* bias_table = (const float*)d_in[12];
    float* out = (float*)d_out;

    // ws layout (bytes): t0 (attn out) | qh | kh | vt | cwb | 4x weight bf16
    char* ws = (char*)d_ws;
    u16*   t0  = (u16*)(ws);
    u16*   qh  = (u16*)(ws + 67108864);
    u16*   kh  = (u16*)(ws + 134217728);
    u16*   vt  = (u16*)(ws + 201326592);
    float* cwb = (float*)(ws + 268435456);
    u16*   wqb = (u16*)(ws + 285212672);
    u16*   wkb = (u16*)(ws + 285736960);
    u16*   wvb = (u16*)(ws + 286261248);
    u16*   wpb = (u16*)(ws + 286785536);

    const int n8_w = (512 * 512) / 8;           // 32,768

    cwb_kernel<<<1024, 256, 0, stream>>>(bias_table, mask, cwb);
    cvt_kernel<<<n8_w / 256, 256, 0, stream>>>(Wq, wqb, n8_w);
    cvt_kernel<<<n8_w / 256, 256, 0, stream>>>(Wk, wkb, n8_w);
    cvt_kernel<<<n8_w / 256, 256, 0, stream>>>(Wv, wvb, n8_w);
    cvt_kernel<<<n8_w / 256, 256, 0, stream>>>(Wp, wpb, n8_w);

    gemm_k<1, 0><<<2048, 256, 0, stream>>>((const void*)q, wqb, bq, SCALE_Q, (void*)qh);
    gemm_k<1, 0><<<2048, 256, 0, stream>>>((const void*)k, wkb, bk, 1.0f,    (void*)kh);
    gemm_k<1, 1><<<2048, 256, 0, stream>>>((const void*)v, wvb, bv, 1.0f,    (void*)vt);

    attn_kernel<<<4096, 256, 0, stream>>>(qh, kh, vt, cwb, t0);

    gemm_k<0, 2><<<2048, 256, 0, stream>>>((const void*)t0, wpb, bp, 1.0f, (void*)out);
}